// Round 3
// baseline (471.245 us; speedup 1.0000x reference)
//
#include <hip/hip_runtime.h>

// MoE-INR fused megakernel, bf16 MFMA (gfx950).
// Inputs are f32 (proven round 1/2). Pipeline: convert the 8 MFMA weight
// matrices to bf16 in d_ws -> fused megakernel (64 rows/block, 256 threads,
// activations LDS-resident as bf16). All scalar-path math (PE, pol_s1, gate,
// biases, final dot, softmax, routing) stays f32 to keep error under the
// 8.1e-4 absmax budget (OMEGA=30 sine layers amplify storage noise ~30x).

typedef short v8s __attribute__((ext_vector_type(8)));
typedef float v4f __attribute__((ext_vector_type(4)));

#define OMEGA_F 30.0f
#define AST 264   // LDS row stride in bf16 elements
#define N_CVT 8

__device__ __forceinline__ float bf2f(unsigned short h) {
  union { unsigned u; float f; } v; v.u = ((unsigned)h) << 16; return v.f;
}
__device__ __forceinline__ unsigned short f2bf(float f) {
  union { float f; unsigned u; } v; v.f = f;
  unsigned r = v.u + 0x7fffu + ((v.u >> 16) & 1u);  // RNE
  return (unsigned short)(r >> 16);
}

struct CvtArgs {
  const float* src[N_CVT];
  unsigned     off[N_CVT];
  unsigned     n[N_CVT];
};

__global__ void convert_kernel(CvtArgs a, unsigned short* __restrict__ dst) {
  const int tid = blockIdx.x * blockDim.x + threadIdx.x;
  const int stride = gridDim.x * blockDim.x;
  for (int k = 0; k < N_CVT; k++) {
    const unsigned n = a.n[k];
    const float* s = a.src[k];
    unsigned short* d = dst + a.off[k];
    for (unsigned i = tid; i < n; i += stride) d[i] = f2bf(s[i]);
  }
}

// ---------------- wave-level GEMM ----------------
// OUT[0:64, oc:oc+N] = act(A[0:64,0:K] @ W[N,K]^T + bias)
// A, OUT, skip are LDS bf16 (stride AST); W is global bf16; bias is global f32.
// Wave tile: 64 rows x (NPW*16) cols. ACT: 0=sin(30z), 1=relu, 2=relu(z+skip)
template<int K, int NPW, int ACT>
__device__ __forceinline__ void wgemm(const unsigned short* A,
                                      unsigned short* OUT, int oc,
                                      const unsigned short* __restrict__ W,
                                      const float* __restrict__ bias,
                                      const unsigned short* skip) {
  const int lane = threadIdx.x & 63;
  const int wave = threadIdx.x >> 6;
  const int m15  = lane & 15;
  const int q    = lane >> 4;
  const int n0   = wave * (NPW * 16);
  v4f acc[4][NPW];
#pragma unroll
  for (int i = 0; i < 4; i++)
#pragma unroll
    for (int j = 0; j < NPW; j++) acc[i][j] = (v4f){0.f, 0.f, 0.f, 0.f};

#pragma unroll
  for (int k0 = 0; k0 < K / 32; ++k0) {
    v8s a[4], b[NPW];
#pragma unroll
    for (int rt = 0; rt < 4; rt++)
      a[rt] = *(const v8s*)(A + (rt * 16 + m15) * AST + k0 * 32 + q * 8);
#pragma unroll
    for (int ct = 0; ct < NPW; ct++)
      b[ct] = *(const v8s*)(W + (size_t)(n0 + ct * 16 + m15) * K + k0 * 32 + q * 8);
#pragma unroll
    for (int rt = 0; rt < 4; rt++)
#pragma unroll
      for (int ct = 0; ct < NPW; ct++)
        acc[rt][ct] = __builtin_amdgcn_mfma_f32_16x16x32_bf16(a[rt], b[ct], acc[rt][ct], 0, 0, 0);
  }

#pragma unroll
  for (int ct = 0; ct < NPW; ct++) {
    const int col = n0 + ct * 16 + m15;
    const float bv = bias[col];
#pragma unroll
    for (int rt = 0; rt < 4; rt++) {
#pragma unroll
      for (int r = 0; r < 4; r++) {
        const int row = rt * 16 + q * 4 + r;
        float z = acc[rt][ct][r] + bv;
        float o;
        if (ACT == 0)      o = __sinf(OMEGA_F * z);
        else if (ACT == 1) o = fmaxf(z, 0.f);
        else { z += bf2f(skip[row * AST + col]); o = fmaxf(z, 0.f); }
        OUT[row * AST + oc + col] = f2bf(o);
      }
    }
  }
}

// Expert layer 2 fused with final 256->1 dot: e2 stays in registers (f32).
__device__ __forceinline__ void wexpert2(const unsigned short* A,
                                         const unsigned short* __restrict__ W,
                                         const float* __restrict__ bias,
                                         const float* __restrict__ wfin,
                                         float* pred) {
  const int lane = threadIdx.x & 63;
  const int wave = threadIdx.x >> 6;
  const int m15  = lane & 15;
  const int q    = lane >> 4;
  const int n0   = wave * 64;
  v4f acc[4][4];
#pragma unroll
  for (int i = 0; i < 4; i++)
#pragma unroll
    for (int j = 0; j < 4; j++) acc[i][j] = (v4f){0.f, 0.f, 0.f, 0.f};

#pragma unroll
  for (int k0 = 0; k0 < 8; ++k0) {
    v8s a[4], b[4];
#pragma unroll
    for (int rt = 0; rt < 4; rt++)
      a[rt] = *(const v8s*)(A + (rt * 16 + m15) * AST + k0 * 32 + q * 8);
#pragma unroll
    for (int ct = 0; ct < 4; ct++)
      b[ct] = *(const v8s*)(W + (size_t)(n0 + ct * 16 + m15) * 256 + k0 * 32 + q * 8);
#pragma unroll
    for (int rt = 0; rt < 4; rt++)
#pragma unroll
      for (int ct = 0; ct < 4; ct++)
        acc[rt][ct] = __builtin_amdgcn_mfma_f32_16x16x32_bf16(a[rt], b[ct], acc[rt][ct], 0, 0, 0);
  }

  float p[4][4];
#pragma unroll
  for (int rt = 0; rt < 4; rt++)
#pragma unroll
    for (int r = 0; r < 4; r++) p[rt][r] = 0.f;
#pragma unroll
  for (int ct = 0; ct < 4; ct++) {
    const int col = n0 + ct * 16 + m15;
    const float bv = bias[col];
    const float wv = wfin[col];
#pragma unroll
    for (int rt = 0; rt < 4; rt++)
#pragma unroll
      for (int r = 0; r < 4; r++) {
        float s = __sinf(OMEGA_F * (acc[rt][ct][r] + bv));
        p[rt][r] += s * wv;
      }
  }
#pragma unroll
  for (int rt = 0; rt < 4; rt++)
#pragma unroll
    for (int r = 0; r < 4; r++) {
      float v = p[rt][r];
      v += __shfl_xor(v, 1);
      v += __shfl_xor(v, 2);
      v += __shfl_xor(v, 4);
      v += __shfl_xor(v, 8);
      if (m15 == 0) atomicAdd(&pred[rt * 16 + q * 4 + r], v);
    }
}

__global__ __launch_bounds__(256, 2) void moe_inr_kernel(
    const float* __restrict__ x,
    const unsigned short* __restrict__ es1w, const float* __restrict__ es1b,
    const unsigned short* __restrict__ es2w, const float* __restrict__ es2b,
    const unsigned short* __restrict__ rf1w, const float* __restrict__ rf1b,
    const unsigned short* __restrict__ rf2w, const float* __restrict__ rf2b,
    const unsigned short* __restrict__ rf3w, const float* __restrict__ rf3b,
    const float* __restrict__ ps1w,          const float* __restrict__ ps1b,
    const unsigned short* __restrict__ ps2w, const float* __restrict__ ps2b,
    const float* __restrict__ gw,            const float* __restrict__ gb,
    const unsigned short* __restrict__ xs1w, const float* __restrict__ xs1b,
    const unsigned short* __restrict__ xs2w, const float* __restrict__ xs2b,
    const float* __restrict__ xfw,           const float* __restrict__ xfb,
    float* __restrict__ out) {
  __shared__ __align__(16) unsigned short P[64 * AST];
  __shared__ __align__(16) unsigned short Q[64 * AST];
  __shared__ float probs[64 * 8];
  __shared__ float yacc[64];
  __shared__ float pred64[64];

  const int t  = threadIdx.x;
  const int r0 = blockIdx.x * 64;

  // Stage 0: positional encoding in f32 from f32 x -> P cols [0,64)
  {
    const int row = t & 63, c = t >> 6;
    const float xv = x[(r0 + row) * 4 + c];
    const float PIf = 3.14159265358979f;
#pragma unroll
    for (int j = 0; j < 8; j++) {
      float ang = xv * (PIf * (float)(1 << j));
      P[row * AST + c * 16 + j]     = f2bf(__sinf(ang));
      P[row * AST + c * 16 + 8 + j] = f2bf(__cosf(ang));
    }
    if (t < 64) yacc[t] = 0.f;
  }
  __syncthreads();
  wgemm<64, 2, 0>(P, P, 64, es1w, es1b, nullptr);        // h1 -> P[64,192)
  __syncthreads();
  wgemm<128, 4, 0>(P + 64, Q, 0, es2w, es2b, nullptr);   // h  -> Q[0,256)
  __syncthreads();
  wgemm<256, 2, 1>(Q, P, 0, rf1w, rf1b, nullptr);        // r1 -> P[0,128)
  __syncthreads();
  wgemm<128, 2, 1>(P, P, 128, rf2w, rf2b, nullptr);      // r2 -> P[128,256)
  __syncthreads();
  wgemm<128, 4, 2>(P + 128, Q, 0, rf3w, rf3b, Q);        // enc_feat -> Q (skip=h)
  __syncthreads();
  // pol_s1 (K=4) fully in f32: pf1 -> P[0,128)
  {
    const int row = t & 63, g = t >> 6;
    const float xv0 = x[(r0 + row) * 4 + 0];
    const float xv1 = x[(r0 + row) * 4 + 1];
    const float xv2 = x[(r0 + row) * 4 + 2];
    const float xv3 = x[(r0 + row) * 4 + 3];
    for (int i = 0; i < 32; i++) {
      int o = g * 32 + i;
      float z = xv0 * ps1w[o * 4 + 0] + xv1 * ps1w[o * 4 + 1] +
                xv2 * ps1w[o * 4 + 2] + xv3 * ps1w[o * 4 + 3] + ps1b[o];
      P[row * AST + o] = f2bf(__sinf(OMEGA_F * z));
    }
  }
  __syncthreads();
  wgemm<128, 2, 0>(P, P, 128, ps2w, ps2b, nullptr);      // pf -> P[128,256)
  __syncthreads();
  // gate (f32 weights)
  {
    const int row = t >> 2, pp = t & 3;
    float lg[7];
#pragma unroll
    for (int j = 0; j < 7; j++) {
      float s = 0.f;
      for (int kk = pp * 96; kk < pp * 96 + 96; ++kk) {
        float v = (kk < 256) ? bf2f(Q[row * AST + kk])
                             : bf2f(P[row * AST + 128 + (kk - 256)]);
        s += v * gw[j * 384 + kk];
      }
      s += __shfl_xor(s, 1);
      s += __shfl_xor(s, 2);
      lg[j] = s;
    }
    if (pp == 0) {
#pragma unroll
      for (int j = 0; j < 7; j++) probs[row * 8 + j] = lg[j] + gb[j];
    }
  }
  __syncthreads();
  if (t < 64) {  // softmax over 7
    float m = probs[t * 8];
#pragma unroll
    for (int j = 1; j < 7; j++) m = fmaxf(m, probs[t * 8 + j]);
    float s = 0.f, e[7];
#pragma unroll
    for (int j = 0; j < 7; j++) { e[j] = __expf(probs[t * 8 + j] - m); s += e[j]; }
    float inv = 1.f / s;
#pragma unroll
    for (int j = 0; j < 7; j++) probs[t * 8 + j] = e[j] * inv;
  }
  // experts: enc_feat stays in Q; e1 -> P; e2+final fused in registers
  for (int ex = 0; ex < 7; ++ex) {
    __syncthreads();
    if (t < 64) pred64[t] = 0.f;
    wgemm<256, 4, 0>(Q, P, 0, xs1w + ex * 65536, xs1b + ex * 256, nullptr);
    __syncthreads();
    wexpert2(P, xs2w + ex * 65536, xs2b + ex * 256, xfw + ex * 256, pred64);
    __syncthreads();
    if (t < 64) yacc[t] += (pred64[t] + xfb[ex]) * probs[t * 8 + ex];
  }
  __syncthreads();
  if (t < 64) out[r0 + t] = yacc[t];
}

extern "C" void kernel_launch(void* const* d_in, const int* in_sizes, int n_in,
                              void* d_out, int out_size, void* d_ws, size_t ws_size,
                              hipStream_t stream) {
  (void)out_size; (void)n_in; (void)ws_size;
  // MFMA weight matrices -> bf16 in d_ws. Indices into d_in:
  // 1 es1w(8192), 3 es2w(32768), 5 rf1w(32768), 7 rf2w(16384), 9 rf3w(32768),
  // 13 ps2w(16384), 17 xs1w(458752), 19 xs2w(458752). Total ~2.11 MB bf16
  // (ws_size >= 2.67 MB proven by round 2's successful convert path).
  const int idx[N_CVT] = {1, 3, 5, 7, 9, 13, 17, 19};
  unsigned off[N_CVT], cur = 0;
  CvtArgs a;
  for (int i = 0; i < N_CVT; i++) {
    off[i] = cur;
    a.src[i] = (const float*)d_in[idx[i]];
    a.off[i] = cur;
    a.n[i]   = (unsigned)in_sizes[idx[i]];
    cur += ((unsigned)in_sizes[idx[i]] + 7u) & ~7u;  // 16B-align each array
  }
  unsigned short* dst = (unsigned short*)d_ws;
  dim3 block(256);
  hipLaunchKernelGGL(convert_kernel, dim3(256), block, 0, stream, a, dst);
  hipLaunchKernelGGL(moe_inr_kernel, dim3(65536 / 64), block, 0, stream,
      (const float*)d_in[0],
      dst + off[0], (const float*)d_in[2],
      dst + off[1], (const float*)d_in[4],
      dst + off[2], (const float*)d_in[6],
      dst + off[3], (const float*)d_in[8],
      dst + off[4], (const float*)d_in[10],
      (const float*)d_in[11], (const float*)d_in[12],
      dst + off[5], (const float*)d_in[14],
      (const float*)d_in[15], (const float*)d_in[16],
      dst + off[6], (const float*)d_in[18],
      dst + off[7], (const float*)d_in[20],
      (const float*)d_in[21], (const float*)d_in[22],
      (float*)d_out);
}

// Round 4
// 461.219 us; speedup vs baseline: 1.0217x; 1.0217x over previous
//
#include <hip/hip_runtime.h>

// MoE-INR fused megakernel, bf16 MFMA (gfx950).
// Round 4: 512 threads (8 waves) per 64-row block, same LDS (70KB -> 2
// blocks/CU) => 16 waves/CU (4/SIMD) to fill latency stalls. Wave col-tiles
// halved vs round 3 (NPW 2/1, wexpert2 32 cols). __launch_bounds__(512,4)
// caps VGPR at 128 for 4 waves/EU.

typedef short v8s __attribute__((ext_vector_type(8)));
typedef float v4f __attribute__((ext_vector_type(4)));

#define OMEGA_F 30.0f
#define AST 264   // LDS row stride in bf16 elements
#define N_CVT 8

__device__ __forceinline__ float bf2f(unsigned short h) {
  union { unsigned u; float f; } v; v.u = ((unsigned)h) << 16; return v.f;
}
__device__ __forceinline__ unsigned short f2bf(float f) {
  union { float f; unsigned u; } v; v.f = f;
  unsigned r = v.u + 0x7fffu + ((v.u >> 16) & 1u);  // RNE
  return (unsigned short)(r >> 16);
}

struct CvtArgs {
  const float* src[N_CVT];
  unsigned     off[N_CVT];
  unsigned     n[N_CVT];
};

__global__ void convert_kernel(CvtArgs a, unsigned short* __restrict__ dst) {
  const int tid = blockIdx.x * blockDim.x + threadIdx.x;
  const int stride = gridDim.x * blockDim.x;
  for (int k = 0; k < N_CVT; k++) {
    const unsigned n = a.n[k];
    const float* s = a.src[k];
    unsigned short* d = dst + a.off[k];
    for (unsigned i = tid; i < n; i += stride) d[i] = f2bf(s[i]);
  }
}

// ---------------- wave-level GEMM (8 waves) ----------------
// OUT[0:64, oc:oc+8*NPW*16] = act(A[0:64,0:K] @ W^T + bias)
// Wave tile: 64 rows x (NPW*16) cols. ACT: 0=sin(30z), 1=relu, 2=relu(z+skip)
template<int K, int NPW, int ACT>
__device__ __forceinline__ void wgemm(const unsigned short* A,
                                      unsigned short* OUT, int oc,
                                      const unsigned short* __restrict__ W,
                                      const float* __restrict__ bias,
                                      const unsigned short* skip) {
  const int lane = threadIdx.x & 63;
  const int wave = threadIdx.x >> 6;
  const int m15  = lane & 15;
  const int q    = lane >> 4;
  const int n0   = wave * (NPW * 16);
  v4f acc[4][NPW];
#pragma unroll
  for (int i = 0; i < 4; i++)
#pragma unroll
    for (int j = 0; j < NPW; j++) acc[i][j] = (v4f){0.f, 0.f, 0.f, 0.f};

#pragma unroll
  for (int k0 = 0; k0 < K / 32; ++k0) {
    v8s a[4], b[NPW];
#pragma unroll
    for (int rt = 0; rt < 4; rt++)
      a[rt] = *(const v8s*)(A + (rt * 16 + m15) * AST + k0 * 32 + q * 8);
#pragma unroll
    for (int ct = 0; ct < NPW; ct++)
      b[ct] = *(const v8s*)(W + (size_t)(n0 + ct * 16 + m15) * K + k0 * 32 + q * 8);
#pragma unroll
    for (int rt = 0; rt < 4; rt++)
#pragma unroll
      for (int ct = 0; ct < NPW; ct++)
        acc[rt][ct] = __builtin_amdgcn_mfma_f32_16x16x32_bf16(a[rt], b[ct], acc[rt][ct], 0, 0, 0);
  }

#pragma unroll
  for (int ct = 0; ct < NPW; ct++) {
    const int col = n0 + ct * 16 + m15;
    const float bv = bias[col];
#pragma unroll
    for (int rt = 0; rt < 4; rt++) {
#pragma unroll
      for (int r = 0; r < 4; r++) {
        const int row = rt * 16 + q * 4 + r;
        float z = acc[rt][ct][r] + bv;
        float o;
        if (ACT == 0)      o = __sinf(OMEGA_F * z);
        else if (ACT == 1) o = fmaxf(z, 0.f);
        else { z += bf2f(skip[row * AST + col]); o = fmaxf(z, 0.f); }
        OUT[row * AST + oc + col] = f2bf(o);
      }
    }
  }
}

// Expert layer 2 fused with final 256->1 dot; 8 waves, 32 cols/wave.
__device__ __forceinline__ void wexpert2(const unsigned short* A,
                                         const unsigned short* __restrict__ W,
                                         const float* __restrict__ bias,
                                         const float* __restrict__ wfin,
                                         float* pred) {
  const int lane = threadIdx.x & 63;
  const int wave = threadIdx.x >> 6;
  const int m15  = lane & 15;
  const int q    = lane >> 4;
  const int n0   = wave * 32;
  v4f acc[4][2];
#pragma unroll
  for (int i = 0; i < 4; i++)
#pragma unroll
    for (int j = 0; j < 2; j++) acc[i][j] = (v4f){0.f, 0.f, 0.f, 0.f};

#pragma unroll
  for (int k0 = 0; k0 < 8; ++k0) {
    v8s a[4], b[2];
#pragma unroll
    for (int rt = 0; rt < 4; rt++)
      a[rt] = *(const v8s*)(A + (rt * 16 + m15) * AST + k0 * 32 + q * 8);
#pragma unroll
    for (int ct = 0; ct < 2; ct++)
      b[ct] = *(const v8s*)(W + (size_t)(n0 + ct * 16 + m15) * 256 + k0 * 32 + q * 8);
#pragma unroll
    for (int rt = 0; rt < 4; rt++)
#pragma unroll
      for (int ct = 0; ct < 2; ct++)
        acc[rt][ct] = __builtin_amdgcn_mfma_f32_16x16x32_bf16(a[rt], b[ct], acc[rt][ct], 0, 0, 0);
  }

  float p[4][4];
#pragma unroll
  for (int rt = 0; rt < 4; rt++)
#pragma unroll
    for (int r = 0; r < 4; r++) p[rt][r] = 0.f;
#pragma unroll
  for (int ct = 0; ct < 2; ct++) {
    const int col = n0 + ct * 16 + m15;
    const float bv = bias[col];
    const float wv = wfin[col];
#pragma unroll
    for (int rt = 0; rt < 4; rt++)
#pragma unroll
      for (int r = 0; r < 4; r++) {
        float s = __sinf(OMEGA_F * (acc[rt][ct][r] + bv));
        p[rt][r] += s * wv;
      }
  }
#pragma unroll
  for (int rt = 0; rt < 4; rt++)
#pragma unroll
    for (int r = 0; r < 4; r++) {
      float v = p[rt][r];
      v += __shfl_xor(v, 1);
      v += __shfl_xor(v, 2);
      v += __shfl_xor(v, 4);
      v += __shfl_xor(v, 8);
      if (m15 == 0) atomicAdd(&pred[rt * 16 + q * 4 + r], v);
    }
}

__global__ __launch_bounds__(512, 4) void moe_inr_kernel(
    const float* __restrict__ x,
    const unsigned short* __restrict__ es1w, const float* __restrict__ es1b,
    const unsigned short* __restrict__ es2w, const float* __restrict__ es2b,
    const unsigned short* __restrict__ rf1w, const float* __restrict__ rf1b,
    const unsigned short* __restrict__ rf2w, const float* __restrict__ rf2b,
    const unsigned short* __restrict__ rf3w, const float* __restrict__ rf3b,
    const float* __restrict__ ps1w,          const float* __restrict__ ps1b,
    const unsigned short* __restrict__ ps2w, const float* __restrict__ ps2b,
    const float* __restrict__ gw,            const float* __restrict__ gb,
    const unsigned short* __restrict__ xs1w, const float* __restrict__ xs1b,
    const unsigned short* __restrict__ xs2w, const float* __restrict__ xs2b,
    const float* __restrict__ xfw,           const float* __restrict__ xfb,
    float* __restrict__ out) {
  __shared__ __align__(16) unsigned short P[64 * AST];
  __shared__ __align__(16) unsigned short Q[64 * AST];
  __shared__ float probs[64 * 8];
  __shared__ float yacc[64];
  __shared__ float pred64[64];

  const int t  = threadIdx.x;
  const int r0 = blockIdx.x * 64;

  // Stage 0: positional encoding in f32 -> P cols [0,64). 512 threads:
  // g = t>>6 in 0..7; c = g&3 (input dim), jh = g>>2 (freq half).
  {
    const int row = t & 63, g = t >> 6, c = g & 3, jh = g >> 2;
    const float xv = x[(r0 + row) * 4 + c];
    const float PIf = 3.14159265358979f;
#pragma unroll
    for (int jj = 0; jj < 4; jj++) {
      const int j = jh * 4 + jj;
      float ang = xv * (PIf * (float)(1 << j));
      P[row * AST + c * 16 + j]     = f2bf(__sinf(ang));
      P[row * AST + c * 16 + 8 + j] = f2bf(__cosf(ang));
    }
    if (t < 64) yacc[t] = 0.f;
  }
  __syncthreads();
  wgemm<64, 1, 0>(P, P, 64, es1w, es1b, nullptr);        // h1 -> P[64,192)
  __syncthreads();
  wgemm<128, 2, 0>(P + 64, Q, 0, es2w, es2b, nullptr);   // h  -> Q[0,256)
  __syncthreads();
  wgemm<256, 1, 1>(Q, P, 0, rf1w, rf1b, nullptr);        // r1 -> P[0,128)
  __syncthreads();
  wgemm<128, 1, 1>(P, P, 128, rf2w, rf2b, nullptr);      // r2 -> P[128,256)
  __syncthreads();
  wgemm<128, 2, 2>(P + 128, Q, 0, rf3w, rf3b, Q);        // enc_feat -> Q (skip=h)
  __syncthreads();
  // pol_s1 (K=4) in f32: pf1 -> P[0,128). 512 threads: 16 outputs each.
  {
    const int row = t & 63, g = t >> 6;
    const float xv0 = x[(r0 + row) * 4 + 0];
    const float xv1 = x[(r0 + row) * 4 + 1];
    const float xv2 = x[(r0 + row) * 4 + 2];
    const float xv3 = x[(r0 + row) * 4 + 3];
    for (int i = 0; i < 16; i++) {
      int o = g * 16 + i;
      float z = xv0 * ps1w[o * 4 + 0] + xv1 * ps1w[o * 4 + 1] +
                xv2 * ps1w[o * 4 + 2] + xv3 * ps1w[o * 4 + 3] + ps1b[o];
      P[row * AST + o] = f2bf(__sinf(OMEGA_F * z));
    }
  }
  __syncthreads();
  wgemm<128, 1, 0>(P, P, 128, ps2w, ps2b, nullptr);      // pf -> P[128,256)
  __syncthreads();
  // gate (f32 weights): 8 partial-threads per row (48 k each)
  {
    const int row = t >> 3, pp = t & 7;
    float lg[7];
#pragma unroll
    for (int j = 0; j < 7; j++) {
      float s = 0.f;
      for (int kk = pp * 48; kk < pp * 48 + 48; ++kk) {
        float v = (kk < 256) ? bf2f(Q[row * AST + kk])
                             : bf2f(P[row * AST + 128 + (kk - 256)]);
        s += v * gw[j * 384 + kk];
      }
      s += __shfl_xor(s, 1);
      s += __shfl_xor(s, 2);
      s += __shfl_xor(s, 4);
      lg[j] = s;
    }
    if (pp == 0) {
#pragma unroll
      for (int j = 0; j < 7; j++) probs[row * 8 + j] = lg[j] + gb[j];
    }
  }
  __syncthreads();
  if (t < 64) {  // softmax over 7
    float m = probs[t * 8];
#pragma unroll
    for (int j = 1; j < 7; j++) m = fmaxf(m, probs[t * 8 + j]);
    float s = 0.f, e[7];
#pragma unroll
    for (int j = 0; j < 7; j++) { e[j] = __expf(probs[t * 8 + j] - m); s += e[j]; }
    float inv = 1.f / s;
#pragma unroll
    for (int j = 0; j < 7; j++) probs[t * 8 + j] = e[j] * inv;
  }
  // experts: enc_feat stays in Q; e1 -> P; e2+final fused in registers
  for (int ex = 0; ex < 7; ++ex) {
    __syncthreads();
    if (t < 64) pred64[t] = 0.f;
    wgemm<256, 2, 0>(Q, P, 0, xs1w + ex * 65536, xs1b + ex * 256, nullptr);
    __syncthreads();
    wexpert2(P, xs2w + ex * 65536, xs2b + ex * 256, xfw + ex * 256, pred64);
    __syncthreads();
    if (t < 64) yacc[t] += (pred64[t] + xfb[ex]) * probs[t * 8 + ex];
  }
  __syncthreads();
  if (t < 64) out[r0 + t] = yacc[t];
}

extern "C" void kernel_launch(void* const* d_in, const int* in_sizes, int n_in,
                              void* d_out, int out_size, void* d_ws, size_t ws_size,
                              hipStream_t stream) {
  (void)out_size; (void)n_in; (void)ws_size;
  const int idx[N_CVT] = {1, 3, 5, 7, 9, 13, 17, 19};
  unsigned off[N_CVT], cur = 0;
  CvtArgs a;
  for (int i = 0; i < N_CVT; i++) {
    off[i] = cur;
    a.src[i] = (const float*)d_in[idx[i]];
    a.off[i] = cur;
    a.n[i]   = (unsigned)in_sizes[idx[i]];
    cur += ((unsigned)in_sizes[idx[i]] + 7u) & ~7u;  // 16B-align each array
  }
  unsigned short* dst = (unsigned short*)d_ws;
  hipLaunchKernelGGL(convert_kernel, dim3(256), dim3(256), 0, stream, a, dst);
  hipLaunchKernelGGL(moe_inr_kernel, dim3(65536 / 64), dim3(512), 0, stream,
      (const float*)d_in[0],
      dst + off[0], (const float*)d_in[2],
      dst + off[1], (const float*)d_in[4],
      dst + off[2], (const float*)d_in[6],
      dst + off[3], (const float*)d_in[8],
      dst + off[4], (const float*)d_in[10],
      (const float*)d_in[11], (const float*)d_in[12],
      dst + off[5], (const float*)d_in[14],
      (const float*)d_in[15], (const float*)d_in[16],
      dst + off[6], (const float*)d_in[18],
      dst + off[7], (const float*)d_in[20],
      (const float*)d_in[21], (const float*)d_in[22],
      (float*)d_out);
}